// Round 1
// 88.111 us; speedup vs baseline: 1.0411x; 1.0411x over previous
//
#include <hip/hip_runtime.h>

// QueryAndGroup — test dims B=2, Nb=2048, N=4096, M=64, K=216, C=32, ns=32.
// Inputs f32; OUTPUT f32: [group_features (L,3+C) | set_new_indices (L,)].
// Round 15: 2-kernel pipeline.
//  - scan_kernel removed: count emits per-block partial sums (4 rows/block);
//    emit redundantly reduces blockSums (<=1024 ints, L2-hot) for its block
//    prefix + grand total nind. Kills one launch + the 1-block scan bubble.
//  - tail-only output zeroing: emit writes rows [0,nind) exactly once and
//    zeroes only [nind*W, L*W) + [nind, L) (float4-vectorized). Removes the
//    double-store of the compacted region (was: count zeroed all 18.9 MB,
//    emit rewrote the head).
// Floor: ~75 us harness poison/restore (256 MB ws fill @41us, flushes L2).
// Trajectory: 606 -> 110 -> 109.6 -> 318 (coop sync REGRESSION) -> 91.2
// -> 96.7 (serial scan-fold REGRESSION, reverted) -> this.

#pragma clang fp contract(off)

typedef unsigned long long u64;

#define MAXN 4096

// ---- count: wave per row; x4-batched ball test; records j's; block sums ----
__global__ __launch_bounds__(256) void count_kernel(
    const float* __restrict__ xyz, const float* __restrict__ new_xyz,
    const float* __restrict__ rois, int* __restrict__ counts,
    int* __restrict__ blockSums, int* __restrict__ ballidx,
    int N, int Nb, int M, int K, int nsample)
{
    __shared__ int plist[4][64];
    __shared__ int scnt[4];
    const int wave = threadIdx.x >> 6;
    const int lane = threadIdx.x & 63;
    const int r = blockIdx.x * 4 + wave;
    const u64 laneLt = (1ull << lane) - 1ull;

    int cntc = 0;
    if (r < N) {
        const int b  = r / Nb;
        const float px = xyz[3 * r + 0];
        const float py = xyz[3 * r + 1];
        const float pz = xyz[3 * r + 2];

        bool pass = false;
        if (lane < M) {
            const float* rp = rois + (size_t)(b * M + lane) * 7;
            const float dx = rp[3], dy = rp[4], dz = rp[5];
            const float r2 = (dx * dx + dy * dy) + dz * dz;   // numpy association
            const float ex = px - rp[0], ey = py - rp[1], ez = pz - rp[2];
            pass = ((ex * ex + ey * ey) + ez * ez) <= r2;
        }
        const u64 roiMask = __ballot(pass);
        if (roiMask) {
            if (pass) plist[wave][__popcll(roiMask & laneLt)] = lane;  // ascending m

            const int P = __popcll(roiMask);
            const int total = P * K;
            const float* nb_ = new_xyz + (size_t)(b * M * K) * 3;
            int* bi = ballidx + (size_t)r * nsample;

            int cnt = 0;
            for (int base = 0; base < total && cnt < nsample; base += 256) {
                bool match[4];
                int jj[4];
                #pragma unroll
                for (int u = 0; u < 4; u++) {      // issue all loads before ballots
                    const int p = base + u * 64 + lane;
                    match[u] = false; jj[u] = 0;
                    if (p < total) {
                        const int ri = p / K;
                        const int k  = p - ri * K;
                        const int j  = plist[wave][ri] * K + k;
                        jj[u] = j;
                        const float* gp = nb_ + (size_t)j * 3;
                        const float ax = px - gp[0], ay = py - gp[1], az = pz - gp[2];
                        match[u] = ((ax * ax + ay * ay) + az * az) <= 1.0f;
                    }
                }
                #pragma unroll
                for (int u = 0; u < 4; u++) {
                    const u64 mm = __ballot(match[u]);
                    const int slot = cnt + __popcll(mm & laneLt);
                    if (match[u] && slot < nsample) bi[slot] = jj[u];
                    cnt += __popcll(mm);
                }
            }
            cntc = cnt > nsample ? nsample : cnt;
        }
        if (lane == 0) counts[r] = cntc;
    }
    if (lane == 0) scnt[wave] = cntc;
    __syncthreads();
    if (threadIdx.x == 0)
        blockSums[blockIdx.x] = scnt[0] + scnt[1] + scnt[2] + scnt[3];
}

// ---- emit: block prefix from blockSums; gather; tail-only zero ----
__global__ __launch_bounds__(256) void emit_kernel(
    const float* __restrict__ xyz, const float* __restrict__ new_xyz,
    const float* __restrict__ features,
    const int* __restrict__ counts, const int* __restrict__ blockSums,
    const int* __restrict__ ballidx,
    float* __restrict__ out_feat, float* __restrict__ out_idx,
    int N, int Nb, int M, int K, int C, int nsample, int numBlocks)
{
    __shared__ int sred[8];
    const int t = threadIdx.x;
    const int lane = t & 63;
    const int wid = t >> 6;

    // Block prefix + grand total over blockSums (<=1024 entries, L2-hot).
    int pre = 0, tot = 0;
    {
        const int b0 = t * 4;
        #pragma unroll
        for (int i = 0; i < 4; i++) {
            const int bb = b0 + i;
            if (bb < numBlocks) {
                const int v = blockSums[bb];
                tot += v;
                if (bb < (int)blockIdx.x) pre += v;
            }
        }
        #pragma unroll
        for (int d = 1; d < 64; d <<= 1) {
            pre += __shfl_xor(pre, d, 64);
            tot += __shfl_xor(tot, d, 64);
        }
        if (lane == 0) { sred[wid] = pre; sred[4 + wid] = tot; }
    }
    __syncthreads();
    const int blockPre = sred[0] + sred[1] + sred[2] + sred[3];
    const int nind     = sred[4] + sred[5] + sred[6] + sred[7];

    const int W = 3 + C;
    const size_t L = (size_t)N * nsample;
    const int r0 = blockIdx.x * 4;
    const int r  = r0 + wid;

    if (r < N) {
        const int cnt = counts[r];
        if (cnt > 0) {
            // intra-block row prefix (<=3 counts, butterfly-summed)
            int rowpre = 0;
            if (lane < wid && (r0 + lane) < N) rowpre = counts[r0 + lane];
            #pragma unroll
            for (int d = 1; d < 64; d <<= 1) rowpre += __shfl_xor(rowpre, d, 64);

            const int b  = r / Nb;
            const int MK = M * K;
            const int obase = blockPre + rowpre;
            const int* bi = ballidx + (size_t)r * nsample;
            const float px = xyz[3 * r + 0];
            const float py = xyz[3 * r + 1];
            const float pz = xyz[3 * r + 2];
            const float* fr = features + (size_t)r * C;
            const float* nb_ = new_xyz + (size_t)b * MK * 3;

            // Feature block: cnt*W contiguous floats at out_feat + obase*W.
            float* dst = out_feat + (size_t)obase * W;
            const int totE = cnt * W;
            for (int idx = lane; idx < totE; idx += 64) {
                const int s = idx / W;
                const int c = idx - s * W;
                const int j = bi[s];
                float v;
                if (c == 0)      v = px - nb_[(size_t)j * 3 + 0];
                else if (c == 1) v = py - nb_[(size_t)j * 3 + 1];
                else if (c == 2) v = pz - nb_[(size_t)j * 3 + 2];
                else             v = fr[c - 3];
                dst[idx] = v;
            }
            for (int s = lane; s < cnt; s += 64)
                out_idx[obase + s] = (float)(b * MK + bi[s]);
        }
    }

    // Tail-only zeroing: rows [0,nind) are fully written above (exact
    // compaction), so only [nind*W, L*W) and [nind, L) need zeros.
    const int gtid = blockIdx.x * 256 + t;
    const int gthreads = gridDim.x * 256;
    {
        const size_t sA = (size_t)nind * W;
        const size_t eA = L * (size_t)W;
        if (sA < eA) {
            const size_t s4 = (sA + 3) & ~(size_t)3;       // 16B-align (floats)
            const size_t headEnd = s4 < eA ? s4 : eA;
            if ((size_t)gtid < headEnd - sA) out_feat[sA + gtid] = 0.0f;
            if (s4 < eA) {
                const size_t nvec = (eA - s4) >> 2;
                float4* p4 = (float4*)(out_feat + s4);
                const float4 z = make_float4(0.0f, 0.0f, 0.0f, 0.0f);
                for (size_t i = gtid; i < nvec; i += gthreads) p4[i] = z;
                const size_t rem = (eA - s4) & 3;
                if ((size_t)gtid < rem) out_feat[eA - rem + gtid] = 0.0f;
            }
        }
    }
    for (size_t i = (size_t)nind + gtid; i < L; i += gthreads)
        out_idx[i] = 0.0f;
}

extern "C" void kernel_launch(void* const* d_in, const int* in_sizes, int n_in,
                              void* d_out, int out_size, void* d_ws, size_t ws_size,
                              hipStream_t stream) {
    if (n_in < 5) return;

    // ---- Role assignment by SIZE (unique on the true test sizes). ----
    int bc = 0;
    for (int i = 1; i < n_in; i++) if (in_sizes[i] < in_sizes[bc]) bc = i;
    const int B = in_sizes[bc];
    if (B < 1) return;

    int xi = -1, nwi = -1, ri = -1, fi = -1;
    int N = 0, M = 0, K = 0, C = 0, nsample = 0;

    for (int rr = 0; rr < n_in && xi < 0; rr++) {
        if (rr == bc) continue;
        if (in_sizes[rr] % (7 * B)) continue;            // rois = B*M*7
        const int M_ = in_sizes[rr] / (7 * B);
        if (M_ < 1 || M_ > 64) continue;
        for (int xx = 0; xx < n_in && xi < 0; xx++) {
            if (xx == bc || xx == rr) continue;
            if (in_sizes[xx] % 3) continue;              // xyz = N*3
            const int N_ = in_sizes[xx] / 3;
            if (N_ < B || N_ % B || N_ > MAXN) continue;
            for (int nn = 0; nn < n_in && xi < 0; nn++) {
                if (nn == bc || nn == rr || nn == xx) continue;
                if (in_sizes[nn] % (3 * B * M_)) continue;   // new_xyz = B*M*K*3
                const int K_ = in_sizes[nn] / (3 * B * M_);
                if (K_ < 1) continue;
                for (int ff = 0; ff < n_in && xi < 0; ff++) {
                    if (ff == bc || ff == rr || ff == xx || ff == nn) continue;
                    if (in_sizes[ff] % N_) continue;         // features = N*C
                    const int C_ = in_sizes[ff] / N_;
                    if (C_ < 1) continue;
                    if (out_size % (4 + C_)) continue;       // out = L*(4+C) f32
                    const long long L_ = (long long)out_size / (4 + C_);
                    if (L_ % N_) continue;
                    const int ns = (int)(L_ / N_);
                    if (ns < 1 || ns > 1024) continue;
                    xi = xx; nwi = nn; ri = rr; fi = ff;
                    N = N_; M = M_; K = K_; C = C_; nsample = ns;
                }
            }
        }
    }
    if (xi < 0) return;

    const float* xyz      = (const float*)d_in[xi];
    const float* new_xyz  = (const float*)d_in[nwi];
    const float* rois     = (const float*)d_in[ri];
    const float* features = (const float*)d_in[fi];
    const int Nb = N / B;

    const size_t L      = (size_t)N * nsample;
    const size_t chunk0 = L * (size_t)(3 + C);

    float* out_feat = (float*)d_out;
    float* out_idx  = out_feat + chunk0;

    const int blocks = (N + 3) / 4;   // one wave per row

    // ws: counts[N] + blockSums[blocks] + ballidx[N*ns]
    const size_t wsNeed = ((size_t)N + (size_t)blocks + (size_t)N * nsample) * sizeof(int);
    if (ws_size < wsNeed) return;
    int* counts    = (int*)d_ws;
    int* blockSums = counts + N;
    int* ballidx   = blockSums + blocks;

    count_kernel<<<blocks, 256, 0, stream>>>(
        xyz, new_xyz, rois, counts, blockSums, ballidx,
        N, Nb, M, K, nsample);
    emit_kernel<<<blocks, 256, 0, stream>>>(
        xyz, new_xyz, features, counts, blockSums, ballidx,
        out_feat, out_idx, N, Nb, M, K, C, nsample, blocks);
}